// Round 2
// baseline (748.924 us; speedup 1.0000x reference)
//
#include <hip/hip_runtime.h>

// ---------------------------------------------------------------------------
// ConvUnrolledISTAEncoder on MI355X (gfx950)
// B=16, CIN=1, T=262144, A=128, K=16 (stride==kernel), ITERS=8, NCLS=3
// Columns: N = B*Tp = 262144 (Tp = 16384). Per column:
//   h_x = Wx @ x_taps + bx            (K=16 conv -> MFMA with zero-padded K)
//   8x:  h = relu(h_x + Wh @ h)       (128x128 matvec per column)
//   out = [softplus(Wk h+bk)+eps ; softplus(Wt h+bt)+eps ; Wp h + bp]
// Round-2: ISTA loop partitioned by ROWS (wave w owns rows [32w,32w+32) for
// all 64 cols) instead of by columns:
//   * Wh A-frags per wave: 32 -> 8  => held in 32 VGPRs, WhLds (32 KB) and
//     its 32 ds_read_b128/iter eliminated (~55% of ISTA LDS traffic).
//   * H double-buffered in LDS (2 x 17 KB), one __syncthreads per iteration.
//   * LDS 49.4 -> 34.8 KB => 4 blocks/CU; __launch_bounds__(256,4).
// Epilogue (Ball, interleaved row-tiles rt=rti*4+w, native-exp softplus,
// magic-div logit store) unchanged from round-1 (verified).
// ---------------------------------------------------------------------------

typedef __attribute__((ext_vector_type(8))) short short8;   // 8 x bf16
typedef __attribute__((ext_vector_type(2))) unsigned uint2v;
typedef __attribute__((ext_vector_type(4))) float float4v;  // MFMA C/D

#define TP 16384
#define THETA_OFF 33554432u   // 16*128*16384
#define LOGIT_OFF 67108864u   // 2*THETA_OFF

// ws layout (bf16 elements):
//  [0      , 16384): Whf  - Wh A-frags:  frag f=(mt*4+ks), elem (f*64+lane)*8+j
//  [16384  , 20480): Wxf  - Wx A-frags (K padded 16->32 with zeros): f=mt
//  [20480  ,102400): Wcf  - [Wk;Wt;Wp] A-frags: f=(rt*4+ks), rt in [0,40)
#define WS_WXF 16384
#define WS_WCF 20480
#define WS_TOTAL 102400

#define HSTRIDE 136   // bf16 elems per column row (16B-aligned, non-pow2 bank stride)

__device__ __forceinline__ short f2bf(float f) {
  union { float f; unsigned u; } v; v.f = f;
  unsigned r = (v.u + 0x7fffu + ((v.u >> 16) & 1u)) >> 16;  // RNE
  return (short)r;
}

// packed f32x2 -> bf16x2 (RNE), single VALU op; no builtin on gfx950
__device__ __forceinline__ unsigned cvt_pk_bf16(float a, float b) {
  unsigned r;
  asm("v_cvt_pk_bf16_f32 %0, %1, %2" : "=v"(r) : "v"(a), "v"(b));
  return r;
}

__global__ void prep_kernel(const float* __restrict__ Wx, const float* __restrict__ Wh,
                            const float* __restrict__ Wk, const float* __restrict__ Wt,
                            const float* __restrict__ Wp, short* __restrict__ wsbf) {
  int i = blockIdx.x * 256 + threadIdx.x;
  if (i >= WS_TOTAL) return;
  float val;
  if (i < WS_WXF) {                       // Wh fragments
    int e = i, f = e >> 9, lane = (e >> 3) & 63, j = e & 7;
    int mt = f >> 2, ks = f & 3, q = lane >> 4, r = lane & 15;
    val = Wh[(mt * 16 + r) * 128 + ks * 32 + q * 8 + j];
  } else if (i < WS_WCF) {                // Wx fragments (zero-pad k>=16)
    int e = i - WS_WXF, mt = e >> 9, lane = (e >> 3) & 63, j = e & 7;
    int q = lane >> 4, r = lane & 15;
    val = (q < 2) ? Wx[(mt * 16 + r) * 16 + q * 8 + j] : 0.0f;
  } else {                                // [Wk;Wt;Wp] fragments
    int e = i - WS_WCF, f = e >> 9, lane = (e >> 3) & 63, j = e & 7;
    int rt = f >> 2, ks = f & 3, q = lane >> 4, r = lane & 15;
    int m = rt * 16 + r, k = ks * 32 + q * 8 + j;
    if (rt < 8)       val = Wk[m * 128 + k];
    else if (rt < 16) val = Wt[(m - 128) * 128 + k];
    else              val = Wp[(m - 256) * 128 + k];
  }
  wsbf[i] = f2bf(val);
}

__global__ __launch_bounds__(256, 4) void ista_kernel(
    const float* __restrict__ x,  const float* __restrict__ bx,
    const float* __restrict__ bk, const float* __restrict__ bt,
    const float* __restrict__ bp, const short* __restrict__ wsbf,
    float* __restrict__ out) {
  // H double buffer: [2][64 cols][HSTRIDE] bf16. Cross-wave shared: wave w
  // writes rows [32w, 32w+32) of every column, reads all rows. One barrier
  // per ISTA iteration (write buf B while others may still read buf A).
  __shared__ short Hbuf[2][64 * HSTRIDE];   // 2 x 17408 B = 34816 B

  const int tid  = threadIdx.x;
  const int w    = tid >> 6;
  const int lane = tid & 63;
  const int q    = lane >> 4;
  const int r    = lane & 15;
  const int g0   = blockIdx.x << 6;     // first global column of block
  const int b    = g0 >> 14;            // batch (64 | 16384, so no straddle)
  const int t0   = g0 & (TP - 1);
  const int mt0  = w << 1;              // this wave's two row-tiles
  const int mt1  = mt0 + 1;

  // --- Wh A-frags for this wave's rows: 8 frags = 32 VGPRs, resident -------
  const short8* whfp = (const short8*)wsbf;
  short8 whf0[4], whf1[4];
#pragma unroll
  for (int ks = 0; ks < 4; ++ks) {
    whf0[ks] = whfp[(((mt0 << 2) + ks) << 6) + lane];
    whf1[ks] = whfp[(((mt1 << 2) + ks) << 6) + lane];
  }

  // --- x B-fragments for ALL 4 column-tiles (rows span all 64 cols) --------
  short8 xfrag[4];
#pragma unroll
  for (int nt = 0; nt < 4; ++nt) {
    union { short8 s; unsigned u[4]; } xu;
    xu.u[0] = xu.u[1] = xu.u[2] = xu.u[3] = 0u;
    if (q < 2) {
      const float* xp = x + (((size_t)(g0 + (nt << 4) + r)) << 4) + (q << 3);
      xu.u[0] = cvt_pk_bf16(xp[0], xp[1]);
      xu.u[1] = cvt_pk_bf16(xp[2], xp[3]);
      xu.u[2] = cvt_pk_bf16(xp[4], xp[5]);
      xu.u[3] = cvt_pk_bf16(xp[6], xp[7]);
    }
    xfrag[nt] = xu.s;
  }

  // --- h_x = Wx @ x + bx for (mt0|mt1) x (4 col-tiles): 8 fp32 frags -------
  const short8* wxfp = (const short8*)(wsbf + WS_WXF);
  const short8 wxf0 = wxfp[(mt0 << 6) + lane];
  const short8 wxf1 = wxfp[(mt1 << 6) + lane];
  const float4v bias0 = *(const float4v*)(bx + (mt0 << 4) + (q << 2));
  const float4v bias1 = *(const float4v*)(bx + (mt1 << 4) + (q << 2));
  float4v hx0[4], hx1[4];
#pragma unroll
  for (int nt = 0; nt < 4; ++nt) {
    hx0[nt] = __builtin_amdgcn_mfma_f32_16x16x32_bf16(wxf0, xfrag[nt], bias0, 0, 0, 0);
    hx1[nt] = __builtin_amdgcn_mfma_f32_16x16x32_bf16(wxf1, xfrag[nt], bias1, 0, 0, 0);
  }

  // --- iteration 1: h = relu(h_x) -> Hbuf[0] -------------------------------
  // C-layout: lane(q,r) reg g holds (row mt*16+q*4+g, col tile_base+r).
#pragma unroll
  for (int nt = 0; nt < 4; ++nt) {
    short* hc = &Hbuf[0][((nt << 4) + r) * HSTRIDE];
    uint2v v0, v1;
    v0[0] = cvt_pk_bf16(fmaxf(hx0[nt][0], 0.0f), fmaxf(hx0[nt][1], 0.0f));
    v0[1] = cvt_pk_bf16(fmaxf(hx0[nt][2], 0.0f), fmaxf(hx0[nt][3], 0.0f));
    v1[0] = cvt_pk_bf16(fmaxf(hx1[nt][0], 0.0f), fmaxf(hx1[nt][1], 0.0f));
    v1[1] = cvt_pk_bf16(fmaxf(hx1[nt][2], 0.0f), fmaxf(hx1[nt][3], 0.0f));
    *(uint2v*)(hc + (mt0 << 4) + (q << 2)) = v0;
    *(uint2v*)(hc + (mt1 << 4) + (q << 2)) = v1;
  }
  __syncthreads();

  // --- iterations 2..8: h = relu(h_x + Wh h), row-partitioned --------------
  const short* hr = Hbuf[0];
  short* hw = Hbuf[1];
#pragma unroll
  for (int it = 1; it < 8; ++it) {
#pragma unroll
    for (int nt = 0; nt < 4; ++nt) {
      const short* hcr = hr + ((nt << 4) + r) * HSTRIDE;
      short8 Bf[4];
#pragma unroll
      for (int ks = 0; ks < 4; ++ks)
        Bf[ks] = *(const short8*)(hcr + (ks << 5) + (q << 3));  // ds_read_b128
      float4v c0 = hx0[nt], c1 = hx1[nt];
#pragma unroll
      for (int ks = 0; ks < 4; ++ks) {
        c0 = __builtin_amdgcn_mfma_f32_16x16x32_bf16(whf0[ks], Bf[ks], c0, 0, 0, 0);
        c1 = __builtin_amdgcn_mfma_f32_16x16x32_bf16(whf1[ks], Bf[ks], c1, 0, 0, 0);
      }
      short* hcw = hw + ((nt << 4) + r) * HSTRIDE;
      uint2v v0, v1;
      v0[0] = cvt_pk_bf16(fmaxf(c0[0], 0.0f), fmaxf(c0[1], 0.0f));
      v0[1] = cvt_pk_bf16(fmaxf(c0[2], 0.0f), fmaxf(c0[3], 0.0f));
      v1[0] = cvt_pk_bf16(fmaxf(c1[0], 0.0f), fmaxf(c1[1], 0.0f));
      v1[1] = cvt_pk_bf16(fmaxf(c1[2], 0.0f), fmaxf(c1[3], 0.0f));
      *(uint2v*)(hcw + (mt0 << 4) + (q << 2)) = v0;             // ds_write_b64
      *(uint2v*)(hcw + (mt1 << 4) + (q << 2)) = v1;
    }
    __syncthreads();
    const short* tmp = hr; hr = hw; hw = (short*)tmp;
  }
  // hr now points at the final H (all 128 rows x 64 cols), barrier passed.

  // --- B-fragments for ALL 64 cols (16 frags = 64 VGPRs) -------------------
  short8 Ball[16];
#pragma unroll
  for (int nt = 0; nt < 4; ++nt)
#pragma unroll
    for (int ks = 0; ks < 4; ++ks)
      Ball[(nt << 2) + ks] =
          *(const short8*)(hr + ((nt << 4) + r) * HSTRIDE + (ks << 5) + (q << 3));

  // --- output projection: row-tiles interleaved rt = rti*4 + w -------------
  // rti 0..1 -> Wk (softplus), 2..3 -> Wt (softplus), 4..9 -> Wp (logits);
  // every wave gets the same mix -> no inter-wave imbalance.
  const short8* wcfp = (const short8*)(wsbf + WS_WCF);
  const size_t brow = ((size_t)b) << 7;  // b*128

  for (int rti = 0; rti < 10; ++rti) {
    const int rt = (rti << 2) + w;       // row-tile of 16 rows
    short8 Af[4];
#pragma unroll
    for (int ks = 0; ks < 4; ++ks) Af[ks] = wcfp[(((rt << 2) + ks) << 6) + lane];
    const int grb = (rt << 4) + (q << 2);
    float4v bias;
    if (rti < 2)      bias = *(const float4v*)(bk + grb);
    else if (rti < 4) bias = *(const float4v*)(bt + grb - 128);
    else              bias = *(const float4v*)(bp + grb - 256);

#pragma unroll
    for (int nt = 0; nt < 4; ++nt) {
      float4v c = {0.0f, 0.0f, 0.0f, 0.0f};
#pragma unroll
      for (int ks = 0; ks < 4; ++ks)
        c = __builtin_amdgcn_mfma_f32_16x16x32_bf16(Af[ks], Ball[(nt << 2) + ks], c, 0, 0, 0);
      const int t = t0 + (nt << 4) + r;

      if (rti < 4) {
        // softplus(v) + eps via native v_exp/v_log (err ~1e-6, band is 3e-2)
        const size_t off  = (rti < 2) ? (size_t)0 : (size_t)THETA_OFF;
        const int    arow = (rti < 2) ? grb : grb - 128;
        float* po = out + off + ((brow + (size_t)arow) << 14) + (size_t)t;
#pragma unroll
        for (int g = 0; g < 4; ++g) {
          const float v  = c[g] + bias[g];
          const float sp = fmaxf(v, 0.0f) + __logf(1.0f + __expf(-fabsf(v))) + 1e-4f;
          po[(size_t)g << 14] = sp;
        }
      } else {
        const unsigned o0  = (unsigned)(grb - 256);
        const unsigned a0  = o0 / 3u;          // magic-div, once per (rti,lane)
        const unsigned rem = o0 - a0 * 3u;
#pragma unroll
        for (int g = 0; g < 4; ++g) {
          const float v = c[g] + bias[g];
          const unsigned cc  = rem + (unsigned)g;     // 0..5
          const unsigned adj = (cc >= 3u) ? 1u : 0u;  // at most one carry
          const unsigned a   = a0 + adj;
          const unsigned ci  = cc - adj * 3u;
          out[(size_t)LOGIT_OFF + ((((brow + (size_t)a) << 14) + (size_t)t) * 3u) + ci] = v;
        }
      }
    }
  }
}

extern "C" void kernel_launch(void* const* d_in, const int* in_sizes, int n_in,
                              void* d_out, int out_size, void* d_ws, size_t ws_size,
                              hipStream_t stream) {
  const float* x  = (const float*)d_in[0];
  const float* Wx = (const float*)d_in[1];
  const float* bx = (const float*)d_in[2];
  const float* Wh = (const float*)d_in[3];
  const float* Wk = (const float*)d_in[4];
  const float* bk = (const float*)d_in[5];
  const float* Wt = (const float*)d_in[6];
  const float* bt = (const float*)d_in[7];
  const float* Wp = (const float*)d_in[8];
  const float* bp = (const float*)d_in[9];
  short* wsbf = (short*)d_ws;
  float* out  = (float*)d_out;

  // ws re-poisoned before every call -> rebuild bf16 fragment tables each time
  hipLaunchKernelGGL(prep_kernel, dim3(WS_TOTAL / 256), dim3(256), 0, stream,
                     Wx, Wh, Wk, Wt, Wp, wsbf);
  // 262144 cols / 64 per block
  hipLaunchKernelGGL(ista_kernel, dim3(4096), dim3(256), 0, stream,
                     x, bx, bk, bt, bp, wsbf, out);
}